// Round 4
// baseline (496.793 us; speedup 1.0000x reference)
//
#include <hip/hip_runtime.h>

#define NN 50000
#define NE 800000
#define KF 256
#define MF 64
#define PKU 264  // LDS row pitch in ushort units (256 + 8 pad)

#define NBK 782    // node buckets of 64: ceil(50000/64)
#define HB 49      // hist/scatter blocks
#define EPB 16384  // edges per hist/scatter block (49*16384 >= 800000)
#define EIDX_CAP (NE + 16 * NBK)  // padded bucket regions

typedef __attribute__((ext_vector_type(8))) short short8;
typedef __attribute__((ext_vector_type(4))) float f32x4;
typedef __attribute__((ext_vector_type(4))) unsigned short us4;

static __device__ __forceinline__ unsigned short f2bf(float x) {
  unsigned int u = __float_as_uint(x);
  u += 0x7FFF + ((u >> 16) & 1);  // round-nearest-even
  return (unsigned short)(u >> 16);
}

// ---------------- MFMA bf16 GEMM: hw[i][j] = (h@W)[i][j] * norm[i] ---------
__global__ __launch_bounds__(256, 2) void gemm_mfma(
    const float* __restrict__ h, const float* __restrict__ W,
    const float* __restrict__ norm, float* __restrict__ hw) {
  __shared__ unsigned short la[64 * PKU];
  __shared__ unsigned short lb[64 * PKU];
  const int t = threadIdx.x;
  const int row0 = blockIdx.x * 64;

#pragma unroll
  for (int it = 0; it < 16; ++it) {
    const int cid = it * 256 + t;
    const int n = cid & 63;
    const int kc = cid >> 6;
    const float w0 = W[(kc * 4 + 0) * MF + n];
    const float w1 = W[(kc * 4 + 1) * MF + n];
    const float w2 = W[(kc * 4 + 2) * MF + n];
    const float w3 = W[(kc * 4 + 3) * MF + n];
    us4 p = {f2bf(w0), f2bf(w1), f2bf(w2), f2bf(w3)};
    *(us4*)&lb[n * PKU + kc * 4] = p;
  }
  {
    const float4* h4 = (const float4*)h;
#pragma unroll
    for (int it = 0; it < 16; ++it) {
      const int cid = it * 256 + t;
      const int r = cid >> 6;
      const int kc = cid & 63;
      const int gr = row0 + r;
      float4 a = make_float4(0.f, 0.f, 0.f, 0.f);
      if (gr < NN) a = h4[(size_t)gr * (KF / 4) + kc];
      us4 p = {f2bf(a.x), f2bf(a.y), f2bf(a.z), f2bf(a.w)};
      *(us4*)&la[r * PKU + kc * 4] = p;
    }
  }
  __syncthreads();

  const int lane = t & 63;
  const int wv = t >> 6;
  const int m = lane & 15;
  const int quad = lane >> 4;

  f32x4 acc[4];
#pragma unroll
  for (int i = 0; i < 4; ++i) acc[i] = (f32x4){0.f, 0.f, 0.f, 0.f};

  const unsigned short* pa = &la[(wv * 16 + m) * PKU + quad * 8];
  const unsigned short* pb = &lb[m * PKU + quad * 8];
#pragma unroll
  for (int k0 = 0; k0 < KF; k0 += 32) {
    const short8 af = *(const short8*)(pa + k0);
#pragma unroll
    for (int nt = 0; nt < 4; ++nt) {
      const short8 bf = *(const short8*)(pb + nt * 16 * PKU + k0);
      acc[nt] = __builtin_amdgcn_mfma_f32_16x16x32_bf16(af, bf, acc[nt], 0, 0, 0);
    }
  }

  const int gm0 = row0 + wv * 16 + quad * 4;
  float nrm[4];
#pragma unroll
  for (int r = 0; r < 4; ++r) nrm[r] = (gm0 + r < NN) ? norm[gm0 + r] : 0.f;
#pragma unroll
  for (int nt = 0; nt < 4; ++nt) {
#pragma unroll
    for (int r = 0; r < 4; ++r) {
      const int gm = gm0 + r;
      if (gm < NN) hw[(size_t)gm * MF + nt * 16 + m] = acc[nt][r] * nrm[r];
    }
  }
}

// ---------------- Bucketing: per-(block,bucket) histogram ------------------
__global__ __launch_bounds__(1024) void bucket_hist(
    const int* __restrict__ dst, int* __restrict__ hist) {
  __shared__ int hh[NBK];
  const int t = threadIdx.x;
  for (int i = t; i < NBK; i += 1024) hh[i] = 0;
  __syncthreads();
  const int base = blockIdx.x * EPB;
#pragma unroll
  for (int i = 0; i < EPB / 1024; ++i) {
    const int e = base + i * 1024 + t;
    if (e < NE) atomicAdd(&hh[dst[e] >> 6], 1);
  }
  __syncthreads();
  for (int i = t; i < NBK; i += 1024) hist[blockIdx.x * NBK + i] = hh[i];
}

// ---------------- Scan bucket totals (64B-padded) + per-block bases --------
__global__ __launch_bounds__(1024) void bucket_base(
    const int* __restrict__ hist, int* __restrict__ blockBase,
    int* __restrict__ bucketStart, int* __restrict__ bucketCnt) {
  __shared__ int s[1024];
  const int t = threadIdx.x;
  int tot = 0;
  if (t < NBK)
    for (int b = 0; b < HB; ++b) tot += hist[b * NBK + t];
  const int pad = (tot + 15) & ~15;  // 16 entries = 64 B alignment
  s[t] = (t < NBK) ? pad : 0;
  __syncthreads();
  for (int off = 1; off < 1024; off <<= 1) {
    const int a = (t >= off) ? s[t - off] : 0;
    __syncthreads();
    s[t] += a;
    __syncthreads();
  }
  if (t < NBK) {
    const int start = s[t] - pad;  // exclusive prefix
    bucketStart[t] = start;
    bucketCnt[t] = tot;
    int run = start;
    for (int b = 0; b < HB; ++b) {
      blockBase[b * NBK + t] = run;
      run += hist[b * NBK + t];
    }
  }
}

// ---------------- Scatter edges into pre-reserved bucket ranges ------------
__global__ __launch_bounds__(1024) void bucket_scatter(
    const int* __restrict__ src, const int* __restrict__ dst,
    const int* __restrict__ blockBase, int* __restrict__ eidx) {
  __shared__ int cur[NBK];
  const int t = threadIdx.x;
  for (int i = t; i < NBK; i += 1024) cur[i] = blockBase[blockIdx.x * NBK + i];
  __syncthreads();
  const int base = blockIdx.x * EPB;
#pragma unroll
  for (int i = 0; i < EPB / 1024; ++i) {
    const int e = base + i * 1024 + t;
    if (e < NE) {
      const int d = dst[e];
      const int pos = atomicAdd(&cur[d >> 6], 1);
      eidx[pos] = (src[e] << 6) | (d & 63);  // src<65536 -> fits 22 bits
    }
  }
}

// ---------------- Aggregate per bucket in LDS + fused epilogue -------------
// One block per 64-node bucket; LDS acc[node][feat] 16 KB; lane = feature.
__global__ __launch_bounds__(512) void bucket_aggregate(
    const int* __restrict__ bucketStart, const int* __restrict__ bucketCnt,
    const int* __restrict__ eidx, const float* __restrict__ hw,
    const float* __restrict__ norm, const float* __restrict__ bias,
    float* __restrict__ out) {
  __shared__ float acc[64 * 64];
  const int t = threadIdx.x;
  const int g = blockIdx.x;
  for (int i = t; i < 4096; i += 512) acc[i] = 0.f;
  __syncthreads();

  const int beg = __builtin_amdgcn_readfirstlane(bucketStart[g]);
  const int cnt = __builtin_amdgcn_readfirstlane(bucketCnt[g]);
  const int lane = t & 63;
  const int wv = t >> 6;  // 0..7

  for (int i0 = wv * 64; i0 < cnt; i0 += 512) {
    const int m = min(64, cnt - i0);
    int v = 0;
    if (lane < m) v = eidx[beg + i0 + lane];  // coalesced
    int j = 0;
    for (; j + 4 <= m; j += 4) {
      const int w0 = __shfl(v, j), w1 = __shfl(v, j + 1);
      const int w2 = __shfl(v, j + 2), w3 = __shfl(v, j + 3);
      const float x0 = hw[(w0 >> 6) * MF + lane];
      const float x1 = hw[(w1 >> 6) * MF + lane];
      const float x2 = hw[(w2 >> 6) * MF + lane];
      const float x3 = hw[(w3 >> 6) * MF + lane];
      atomicAdd(&acc[(w0 & 63) * MF + lane], x0);
      atomicAdd(&acc[(w1 & 63) * MF + lane], x1);
      atomicAdd(&acc[(w2 & 63) * MF + lane], x2);
      atomicAdd(&acc[(w3 & 63) * MF + lane], x3);
    }
    for (; j < m; ++j) {
      const int w0 = __shfl(v, j);
      atomicAdd(&acc[(w0 & 63) * MF + lane], hw[(w0 >> 6) * MF + lane]);
    }
  }
  __syncthreads();

  // Epilogue: relu(acc*norm + bias), 1024 float4s by 512 threads.
  const float4* a4 = (const float4*)acc;
#pragma unroll
  for (int k = 0; k < 2; ++k) {
    const int q = k * 512 + t;
    const int nl = q >> 4;  // local node
    const int f4 = q & 15;
    const int vtx = g * 64 + nl;
    if (vtx < NN) {
      const float n = norm[vtx];
      const float4 a = a4[q];
      const float4 b = ((const float4*)bias)[f4];
      float4 o;
      o.x = fmaxf(a.x * n + b.x, 0.f);
      o.y = fmaxf(a.y * n + b.y, 0.f);
      o.z = fmaxf(a.z * n + b.z, 0.f);
      o.w = fmaxf(a.w * n + b.w, 0.f);
      ((float4*)out)[(size_t)vtx * (MF / 4) + f4] = o;
    }
  }
}

extern "C" void kernel_launch(void* const* d_in, const int* in_sizes, int n_in,
                              void* d_out, int out_size, void* d_ws, size_t ws_size,
                              hipStream_t stream) {
  const float* h = (const float*)d_in[0];
  const float* norm = (const float*)d_in[1];
  const float* W = (const float*)d_in[2];
  const float* bias = (const float*)d_in[3];
  const int* src = (const int*)d_in[4];
  const int* dst = (const int*)d_in[5];
  float* out = (float*)d_out;

  // Workspace layout (all 16-element aligned)
  float* hw = (float*)d_ws;                         // NN*MF floats
  int* hist = (int*)(hw + (size_t)NN * MF);         // HB*NBK
  int* blockBase = hist + ((HB * NBK + 15) & ~15);  // HB*NBK
  int* bucketStart = blockBase + ((HB * NBK + 15) & ~15);  // NBK
  int* bucketCnt = bucketStart + ((NBK + 15) & ~15);       // NBK
  int* eidx = bucketCnt + ((NBK + 15) & ~15);              // EIDX_CAP
  const size_t need =
      ((size_t)NN * MF + 2 * ((HB * NBK + 15) & ~15) +
       2 * ((NBK + 15) & ~15) + EIDX_CAP) * 4;
  if (ws_size < need) return;

  gemm_mfma<<<(NN + 63) / 64, 256, 0, stream>>>(h, W, norm, hw);  // 782 blocks
  bucket_hist<<<HB, 1024, 0, stream>>>(dst, hist);
  bucket_base<<<1, 1024, 0, stream>>>(hist, blockBase, bucketStart, bucketCnt);
  bucket_scatter<<<HB, 1024, 0, stream>>>(src, dst, blockBase, eidx);
  bucket_aggregate<<<NBK, 512, 0, stream>>>(bucketStart, bucketCnt, eidx, hw,
                                            norm, bias, out);
}

// Round 5
// 188.702 us; speedup vs baseline: 2.6327x; 2.6327x over previous
//
#include <hip/hip_runtime.h>

#define NN 50000
#define NE 800000
#define KF 256
#define MF 64
#define PKU 264  // LDS row pitch in ushort units (256 + 8 pad)

#define NBK 782    // node buckets of 64: ceil(50000/64)
#define HB 49      // hist/scatter blocks
#define EPB 16384  // edges per hist/scatter block (49*16384 >= 800000)
#define EIDX_CAP (NE + 16 * NBK)  // padded bucket regions

typedef __attribute__((ext_vector_type(8))) short short8;
typedef __attribute__((ext_vector_type(4))) float f32x4;
typedef __attribute__((ext_vector_type(4))) unsigned short us4;

static __device__ __forceinline__ unsigned short f2bf(float x) {
  unsigned int u = __float_as_uint(x);
  u += 0x7FFF + ((u >> 16) & 1);  // round-nearest-even
  return (unsigned short)(u >> 16);
}

// ---------------- MFMA bf16 GEMM: hw[i][j] = (h@W)[i][j] * norm[i] ---------
__global__ __launch_bounds__(256, 2) void gemm_mfma(
    const float* __restrict__ h, const float* __restrict__ W,
    const float* __restrict__ norm, float* __restrict__ hw) {
  __shared__ unsigned short la[64 * PKU];
  __shared__ unsigned short lb[64 * PKU];
  const int t = threadIdx.x;
  const int row0 = blockIdx.x * 64;

#pragma unroll
  for (int it = 0; it < 16; ++it) {
    const int cid = it * 256 + t;
    const int n = cid & 63;
    const int kc = cid >> 6;
    const float w0 = W[(kc * 4 + 0) * MF + n];
    const float w1 = W[(kc * 4 + 1) * MF + n];
    const float w2 = W[(kc * 4 + 2) * MF + n];
    const float w3 = W[(kc * 4 + 3) * MF + n];
    us4 p = {f2bf(w0), f2bf(w1), f2bf(w2), f2bf(w3)};
    *(us4*)&lb[n * PKU + kc * 4] = p;
  }
  {
    const float4* h4 = (const float4*)h;
#pragma unroll
    for (int it = 0; it < 16; ++it) {
      const int cid = it * 256 + t;
      const int r = cid >> 6;
      const int kc = cid & 63;
      const int gr = row0 + r;
      float4 a = make_float4(0.f, 0.f, 0.f, 0.f);
      if (gr < NN) a = h4[(size_t)gr * (KF / 4) + kc];
      us4 p = {f2bf(a.x), f2bf(a.y), f2bf(a.z), f2bf(a.w)};
      *(us4*)&la[r * PKU + kc * 4] = p;
    }
  }
  __syncthreads();

  const int lane = t & 63;
  const int wv = t >> 6;
  const int m = lane & 15;
  const int quad = lane >> 4;

  f32x4 acc[4];
#pragma unroll
  for (int i = 0; i < 4; ++i) acc[i] = (f32x4){0.f, 0.f, 0.f, 0.f};

  const unsigned short* pa = &la[(wv * 16 + m) * PKU + quad * 8];
  const unsigned short* pb = &lb[m * PKU + quad * 8];
#pragma unroll
  for (int k0 = 0; k0 < KF; k0 += 32) {
    const short8 af = *(const short8*)(pa + k0);
#pragma unroll
    for (int nt = 0; nt < 4; ++nt) {
      const short8 bf = *(const short8*)(pb + nt * 16 * PKU + k0);
      acc[nt] = __builtin_amdgcn_mfma_f32_16x16x32_bf16(af, bf, acc[nt], 0, 0, 0);
    }
  }

  const int gm0 = row0 + wv * 16 + quad * 4;
  float nrm[4];
#pragma unroll
  for (int r = 0; r < 4; ++r) nrm[r] = (gm0 + r < NN) ? norm[gm0 + r] : 0.f;
#pragma unroll
  for (int nt = 0; nt < 4; ++nt) {
#pragma unroll
    for (int r = 0; r < 4; ++r) {
      const int gm = gm0 + r;
      if (gm < NN) hw[(size_t)gm * MF + nt * 16 + m] = acc[nt][r] * nrm[r];
    }
  }
}

// ---------------- per-(block,bucket) histogram, TRANSPOSED layout ----------
// histT[bucket*64 + block] so scan_bases reads per-thread contiguous.
__global__ __launch_bounds__(1024) void bucket_hist(
    const int* __restrict__ dst, int* __restrict__ histT) {
  __shared__ int hh[NBK];
  const int t = threadIdx.x;
  for (int i = t; i < NBK; i += 1024) hh[i] = 0;
  __syncthreads();
  const int base = blockIdx.x * EPB;
#pragma unroll
  for (int i = 0; i < EPB / 1024; ++i) {
    const int e = base + i * 1024 + t;
    if (e < NE) atomicAdd(&hh[dst[e] >> 6], 1);
  }
  __syncthreads();
  for (int i = t; i < NBK; i += 1024) histT[i * 64 + blockIdx.x] = hh[i];
}

// ---------------- Scan bucket totals + per-(block,bucket) bases ------------
__global__ __launch_bounds__(1024) void scan_bases(
    const int* __restrict__ histT, int* __restrict__ blockBase,
    int* __restrict__ bucketStart, int* __restrict__ bucketCnt) {
  __shared__ int s[1024];
  const int t = threadIdx.x;
  int tot = 0;
  if (t < NBK) {
    const int* hp = histT + t * 64;  // contiguous per thread
#pragma unroll
    for (int b = 0; b < HB; ++b) tot += hp[b];
  }
  const int pad = (tot + 15) & ~15;  // 64 B-align bucket regions
  s[t] = (t < NBK) ? pad : 0;
  __syncthreads();
  for (int off = 1; off < 1024; off <<= 1) {
    const int a = (t >= off) ? s[t - off] : 0;
    __syncthreads();
    s[t] += a;
    __syncthreads();
  }
  if (t < NBK) {
    const int start = s[t] - pad;  // exclusive prefix
    bucketStart[t] = start;
    bucketCnt[t] = tot;
    const int* hp = histT + t * 64;
    int run = start;
#pragma unroll
    for (int b = 0; b < HB; ++b) {
      blockBase[b * NBK + t] = run;
      run += hp[b];
    }
  }
}

// ---------------- Scatter edges into pre-reserved bucket ranges ------------
// Each block writes ~21-entry contiguous runs per bucket: no cross-block
// (cross-XCD) cache-line sharing -> minimal write amplification.
__global__ __launch_bounds__(1024) void bucket_scatter(
    const int* __restrict__ src, const int* __restrict__ dst,
    const int* __restrict__ blockBase, int* __restrict__ eidx) {
  __shared__ int cur[NBK];
  const int t = threadIdx.x;
  for (int i = t; i < NBK; i += 1024) cur[i] = blockBase[blockIdx.x * NBK + i];
  __syncthreads();
  const int base = blockIdx.x * EPB;
#pragma unroll
  for (int i = 0; i < EPB / 1024; ++i) {
    const int e = base + i * 1024 + t;
    if (e < NE) {
      const int d = dst[e];
      const int pos = atomicAdd(&cur[d >> 6], 1);
      eidx[pos] = (src[e] << 6) | (d & 63);  // src<65536 -> fits
    }
  }
}

// ---------------- Per-bucket counting sort -> exact per-node CSR -----------
// One block per bucket. All global reads/writes coalesced within the
// bucket's single-owner 4 KB region.
__global__ __launch_bounds__(256) void csr_sort(
    const int* __restrict__ bucketStart, const int* __restrict__ bucketCnt,
    const int* __restrict__ eidx, int* __restrict__ eidx2,
    int* __restrict__ offs, int* __restrict__ ends) {
  __shared__ int hcnt[64];
  __shared__ int cur[64];
  const int t = threadIdx.x;
  const int g = blockIdx.x;
  const int beg = __builtin_amdgcn_readfirstlane(bucketStart[g]);
  const int cnt = __builtin_amdgcn_readfirstlane(bucketCnt[g]);
  if (t < 64) hcnt[t] = 0;
  __syncthreads();
  for (int i = t; i < cnt; i += 256) atomicAdd(&hcnt[eidx[beg + i] & 63], 1);
  __syncthreads();
  if (t < 64) {  // wave 0: 64-lane exclusive scan
    const int v = hcnt[t];
    int incl = v;
#pragma unroll
    for (int off = 1; off < 64; off <<= 1) {
      const int u = __shfl_up(incl, off, 64);
      if (t >= off) incl += u;
    }
    const int excl = incl - v;
    cur[t] = excl;
    const int vtx = g * 64 + t;
    if (vtx < NN) {
      offs[vtx] = beg + excl;
      ends[vtx] = beg + excl + v;
    }
  }
  __syncthreads();
  for (int i = t; i < cnt; i += 256) {
    const int val = eidx[beg + i];
    const int p = atomicAdd(&cur[val & 63], 1);
    eidx2[beg + p] = val >> 6;  // src node id
  }
}

// ---------------- CSR gather + fused epilogue ------------------------------
// One wave per node, lane = feature. Edge indices: wave-uniform scalar
// loads; hw rows: coalesced 256 B vector loads. Deterministic sum order.
__global__ __launch_bounds__(256) void gather_finalize(
    const int* __restrict__ offs, const int* __restrict__ ends,
    const int* __restrict__ eidx2, const float* __restrict__ hw,
    const float* __restrict__ norm, const float* __restrict__ bias,
    float* __restrict__ out) {
  const int t = threadIdx.x;
  const int lane = t & 63;
  const int v = blockIdx.x * 4 + (t >> 6);
  if (v >= NN) return;
  const int beg = __builtin_amdgcn_readfirstlane(offs[v]);
  const int end = __builtin_amdgcn_readfirstlane(ends[v]);
  float acc = 0.f;
  int i = beg;
  for (; i + 8 <= end; i += 8) {  // 8 row-loads in flight
    const int s0 = eidx2[i], s1 = eidx2[i + 1], s2 = eidx2[i + 2], s3 = eidx2[i + 3];
    const int s4 = eidx2[i + 4], s5 = eidx2[i + 5], s6 = eidx2[i + 6], s7 = eidx2[i + 7];
    const float x0 = hw[(size_t)s0 * MF + lane];
    const float x1 = hw[(size_t)s1 * MF + lane];
    const float x2 = hw[(size_t)s2 * MF + lane];
    const float x3 = hw[(size_t)s3 * MF + lane];
    const float x4 = hw[(size_t)s4 * MF + lane];
    const float x5 = hw[(size_t)s5 * MF + lane];
    const float x6 = hw[(size_t)s6 * MF + lane];
    const float x7 = hw[(size_t)s7 * MF + lane];
    acc += x0; acc += x1; acc += x2; acc += x3;
    acc += x4; acc += x5; acc += x6; acc += x7;
  }
  for (; i + 2 <= end; i += 2) {
    const int s0 = eidx2[i], s1 = eidx2[i + 1];
    const float x0 = hw[(size_t)s0 * MF + lane];
    const float x1 = hw[(size_t)s1 * MF + lane];
    acc += x0; acc += x1;
  }
  if (i < end) acc += hw[(size_t)eidx2[i] * MF + lane];
  const float o = acc * norm[v] + bias[lane];
  out[(size_t)v * MF + lane] = fmaxf(o, 0.f);
}

extern "C" void kernel_launch(void* const* d_in, const int* in_sizes, int n_in,
                              void* d_out, int out_size, void* d_ws, size_t ws_size,
                              hipStream_t stream) {
  const float* h = (const float*)d_in[0];
  const float* norm = (const float*)d_in[1];
  const float* W = (const float*)d_in[2];
  const float* bias = (const float*)d_in[3];
  const int* src = (const int*)d_in[4];
  const int* dst = (const int*)d_in[5];
  float* out = (float*)d_out;

  // Workspace layout (16-element aligned chunks)
  float* hw = (float*)d_ws;                          // NN*MF floats (12.8 MB)
  int* histT = (int*)(hw + (size_t)NN * MF);         // NBK*64
  int* blockBase = histT + NBK * 64;                 // HB*NBK (+pad)
  int* bucketStart = blockBase + ((HB * NBK + 15) & ~15);
  int* bucketCnt = bucketStart + ((NBK + 15) & ~15);
  int* offs = bucketCnt + ((NBK + 15) & ~15);        // NN
  int* ends = offs + ((NN + 15) & ~15);              // NN
  int* eidx = ends + ((NN + 15) & ~15);              // EIDX_CAP
  int* eidx2 = eidx + ((EIDX_CAP + 15) & ~15);       // EIDX_CAP
  const size_t need =
      ((size_t)NN * MF + NBK * 64 + ((HB * NBK + 15) & ~15) +
       2 * ((NBK + 15) & ~15) + 2 * ((NN + 15) & ~15) +
       2 * ((EIDX_CAP + 15) & ~15)) * 4;
  if (ws_size < need) return;

  gemm_mfma<<<(NN + 63) / 64, 256, 0, stream>>>(h, W, norm, hw);
  bucket_hist<<<HB, 1024, 0, stream>>>(dst, histT);
  scan_bases<<<1, 1024, 0, stream>>>(histT, blockBase, bucketStart, bucketCnt);
  bucket_scatter<<<HB, 1024, 0, stream>>>(src, dst, blockBase, eidx);
  csr_sort<<<NBK, 256, 0, stream>>>(bucketStart, bucketCnt, eidx, eidx2, offs, ends);
  gather_finalize<<<(NN + 3) / 4, 256, 0, stream>>>(offs, ends, eidx2, hw, norm, bias, out);
}

// Round 6
// 177.731 us; speedup vs baseline: 2.7952x; 1.0617x over previous
//
#include <hip/hip_runtime.h>

#define NN 50000
#define NE 800000
#define KF 256
#define MF 64
#define PKU 264  // LDS row pitch in ushort units (256 + 8 pad)

#define NBK 782    // node buckets of 64: ceil(50000/64)
#define HB 49      // hist/scatter blocks
#define EPB 16384  // edges per hist/scatter block (49*16384 >= 800000)
#define GB 782     // gemm blocks (ceil(50000/64))
#define EIDX_CAP (NE + 16 * NBK)  // padded bucket regions

typedef __attribute__((ext_vector_type(8))) short short8;
typedef __attribute__((ext_vector_type(4))) float f32x4;
typedef __attribute__((ext_vector_type(4))) unsigned short us4;

static __device__ __forceinline__ unsigned short f2bf(float x) {
  unsigned int u = __float_as_uint(x);
  u += 0x7FFF + ((u >> 16) & 1);  // round-nearest-even
  return (unsigned short)(u >> 16);
}
static __device__ __forceinline__ float bf2f(unsigned short u) {
  return __uint_as_float(((unsigned int)u) << 16);
}

// ------- Fused: MFMA bf16 GEMM (blocks 0..781) + edge histogram (782..830) -
// gemm: hw[i][j] = (h@W)[i][j] * norm[i], stored bf16.
// hist: per-(block,bucket) counts, transposed histT[bucket*64+block].
__global__ __launch_bounds__(256, 2) void gemm_hist(
    const float* __restrict__ h, const float* __restrict__ W,
    const float* __restrict__ norm, const int* __restrict__ dst,
    unsigned short* __restrict__ hwb, int* __restrict__ histT) {
  __shared__ unsigned short la[64 * PKU];
  __shared__ unsigned short lb[64 * PKU];
  __shared__ int hh[NBK];
  const int t = threadIdx.x;

  if (blockIdx.x >= GB) {  // ---- histogram branch ----
    const int hb = blockIdx.x - GB;
    for (int i = t; i < NBK; i += 256) hh[i] = 0;
    __syncthreads();
    const int base = hb * EPB;
#pragma unroll
    for (int i = 0; i < EPB / 256; ++i) {
      const int e = base + i * 256 + t;
      if (e < NE) atomicAdd(&hh[dst[e] >> 6], 1);
    }
    __syncthreads();
    for (int i = t; i < NBK; i += 256) histT[i * 64 + hb] = hh[i];
    return;
  }

  // ---- GEMM branch ----
  const int row0 = blockIdx.x * 64;
#pragma unroll
  for (int it = 0; it < 16; ++it) {
    const int cid = it * 256 + t;
    const int n = cid & 63;
    const int kc = cid >> 6;
    const float w0 = W[(kc * 4 + 0) * MF + n];
    const float w1 = W[(kc * 4 + 1) * MF + n];
    const float w2 = W[(kc * 4 + 2) * MF + n];
    const float w3 = W[(kc * 4 + 3) * MF + n];
    us4 p = {f2bf(w0), f2bf(w1), f2bf(w2), f2bf(w3)};
    *(us4*)&lb[n * PKU + kc * 4] = p;
  }
  {
    const float4* h4 = (const float4*)h;
#pragma unroll
    for (int it = 0; it < 16; ++it) {
      const int cid = it * 256 + t;
      const int r = cid >> 6;
      const int kc = cid & 63;
      const int gr = row0 + r;
      float4 a = make_float4(0.f, 0.f, 0.f, 0.f);
      if (gr < NN) a = h4[(size_t)gr * (KF / 4) + kc];
      us4 p = {f2bf(a.x), f2bf(a.y), f2bf(a.z), f2bf(a.w)};
      *(us4*)&la[r * PKU + kc * 4] = p;
    }
  }
  __syncthreads();

  const int lane = t & 63;
  const int wv = t >> 6;
  const int m = lane & 15;
  const int quad = lane >> 4;

  f32x4 acc[4];
#pragma unroll
  for (int i = 0; i < 4; ++i) acc[i] = (f32x4){0.f, 0.f, 0.f, 0.f};

  const unsigned short* pa = &la[(wv * 16 + m) * PKU + quad * 8];
  const unsigned short* pb = &lb[m * PKU + quad * 8];
#pragma unroll
  for (int k0 = 0; k0 < KF; k0 += 32) {
    const short8 af = *(const short8*)(pa + k0);
#pragma unroll
    for (int nt = 0; nt < 4; ++nt) {
      const short8 bf = *(const short8*)(pb + nt * 16 * PKU + k0);
      acc[nt] = __builtin_amdgcn_mfma_f32_16x16x32_bf16(af, bf, acc[nt], 0, 0, 0);
    }
  }

  const int gm0 = row0 + wv * 16 + quad * 4;
  float nrm[4];
#pragma unroll
  for (int r = 0; r < 4; ++r) nrm[r] = (gm0 + r < NN) ? norm[gm0 + r] : 0.f;
#pragma unroll
  for (int nt = 0; nt < 4; ++nt) {
#pragma unroll
    for (int r = 0; r < 4; ++r) {
      const int gm = gm0 + r;
      if (gm < NN) hwb[(size_t)gm * MF + nt * 16 + m] = f2bf(acc[nt][r] * nrm[r]);
    }
  }
}

// ------- Scatter with integrated scan: every block recomputes bucket bases -
// Reserved per-(block,bucket) ranges -> contention-free, ~21-entry
// contiguous runs (no cross-XCD line sharing). Block 0 publishes
// bucketStart/bucketCnt for the next stages.
__global__ __launch_bounds__(1024) void scatter_scan(
    const int* __restrict__ src, const int* __restrict__ dst,
    const int* __restrict__ histT, int* __restrict__ eidx,
    int* __restrict__ bucketStart, int* __restrict__ bucketCnt) {
  __shared__ int s[1024];
  __shared__ int cur[NBK];
  const int t = threadIdx.x;
  int tot = 0, mine = 0;
  if (t < NBK) {
    const int* hp = histT + t * 64;  // contiguous per thread
#pragma unroll
    for (int b = 0; b < HB; ++b) {
      const int v = hp[b];
      if (b < (int)blockIdx.x) mine += v;
      tot += v;
    }
  }
  const int pad = (tot + 15) & ~15;  // 64 B-align bucket regions
  s[t] = (t < NBK) ? pad : 0;
  __syncthreads();
  for (int off = 1; off < 1024; off <<= 1) {
    const int a = (t >= off) ? s[t - off] : 0;
    __syncthreads();
    s[t] += a;
    __syncthreads();
  }
  if (t < NBK) {
    const int start = s[t] - pad;  // exclusive prefix
    cur[t] = start + mine;
    if (blockIdx.x == 0) {
      bucketStart[t] = start;
      bucketCnt[t] = tot;
    }
  }
  __syncthreads();
  const int base = blockIdx.x * EPB;
#pragma unroll
  for (int i = 0; i < EPB / 1024; ++i) {
    const int e = base + i * 1024 + t;
    if (e < NE) {
      const int d = dst[e];
      const int pos = atomicAdd(&cur[d >> 6], 1);
      eidx[pos] = (src[e] << 6) | (d & 63);  // src<65536 -> fits
    }
  }
}

// ------- Per-bucket counting sort -> exact per-node CSR --------------------
__global__ __launch_bounds__(256) void csr_sort(
    const int* __restrict__ bucketStart, const int* __restrict__ bucketCnt,
    const int* __restrict__ eidx, int* __restrict__ eidx2,
    int* __restrict__ offs, int* __restrict__ ends) {
  __shared__ int hcnt[64];
  __shared__ int cur[64];
  const int t = threadIdx.x;
  const int g = blockIdx.x;
  const int beg = __builtin_amdgcn_readfirstlane(bucketStart[g]);
  const int cnt = __builtin_amdgcn_readfirstlane(bucketCnt[g]);
  if (t < 64) hcnt[t] = 0;
  __syncthreads();
  for (int i = t; i < cnt; i += 256) atomicAdd(&hcnt[eidx[beg + i] & 63], 1);
  __syncthreads();
  if (t < 64) {  // wave 0: 64-lane exclusive scan
    const int v = hcnt[t];
    int incl = v;
#pragma unroll
    for (int off = 1; off < 64; off <<= 1) {
      const int u = __shfl_up(incl, off, 64);
      if (t >= off) incl += u;
    }
    const int excl = incl - v;
    cur[t] = excl;
    const int vtx = g * 64 + t;
    if (vtx < NN) {
      offs[vtx] = beg + excl;
      ends[vtx] = beg + excl + v;
    }
  }
  __syncthreads();
  for (int i = t; i < cnt; i += 256) {
    const int val = eidx[beg + i];
    const int p = atomicAdd(&cur[val & 63], 1);
    eidx2[beg + p] = val >> 6;  // src node id
  }
}

// ------- CSR gather (bf16 rows) + fused epilogue ---------------------------
// One wave per node, lane = feature. Edge ids: wave-uniform scalar loads
// (merged s_load_dwordx); rows: coalesced 128 B bf16 loads.
__global__ __launch_bounds__(256) void gather_finalize(
    const int* __restrict__ offs, const int* __restrict__ ends,
    const int* __restrict__ eidx2, const unsigned short* __restrict__ hwb,
    const float* __restrict__ norm, const float* __restrict__ bias,
    float* __restrict__ out) {
  const int t = threadIdx.x;
  const int lane = t & 63;
  const int v = blockIdx.x * 4 + (t >> 6);
  if (v >= NN) return;
  const int beg = __builtin_amdgcn_readfirstlane(offs[v]);
  const int end = __builtin_amdgcn_readfirstlane(ends[v]);
  float acc = 0.f;
  int i = beg;
  for (; i + 8 <= end; i += 8) {  // 8 row-loads in flight
    const int s0 = eidx2[i], s1 = eidx2[i + 1], s2 = eidx2[i + 2], s3 = eidx2[i + 3];
    const int s4 = eidx2[i + 4], s5 = eidx2[i + 5], s6 = eidx2[i + 6], s7 = eidx2[i + 7];
    const unsigned short x0 = hwb[(size_t)s0 * MF + lane];
    const unsigned short x1 = hwb[(size_t)s1 * MF + lane];
    const unsigned short x2 = hwb[(size_t)s2 * MF + lane];
    const unsigned short x3 = hwb[(size_t)s3 * MF + lane];
    const unsigned short x4 = hwb[(size_t)s4 * MF + lane];
    const unsigned short x5 = hwb[(size_t)s5 * MF + lane];
    const unsigned short x6 = hwb[(size_t)s6 * MF + lane];
    const unsigned short x7 = hwb[(size_t)s7 * MF + lane];
    acc += bf2f(x0); acc += bf2f(x1); acc += bf2f(x2); acc += bf2f(x3);
    acc += bf2f(x4); acc += bf2f(x5); acc += bf2f(x6); acc += bf2f(x7);
  }
  for (; i + 2 <= end; i += 2) {
    const int s0 = eidx2[i], s1 = eidx2[i + 1];
    const unsigned short x0 = hwb[(size_t)s0 * MF + lane];
    const unsigned short x1 = hwb[(size_t)s1 * MF + lane];
    acc += bf2f(x0); acc += bf2f(x1);
  }
  if (i < end) acc += bf2f(hwb[(size_t)eidx2[i] * MF + lane]);
  const float o = acc * norm[v] + bias[lane];
  out[(size_t)v * MF + lane] = fmaxf(o, 0.f);
}

extern "C" void kernel_launch(void* const* d_in, const int* in_sizes, int n_in,
                              void* d_out, int out_size, void* d_ws, size_t ws_size,
                              hipStream_t stream) {
  const float* h = (const float*)d_in[0];
  const float* norm = (const float*)d_in[1];
  const float* W = (const float*)d_in[2];
  const float* bias = (const float*)d_in[3];
  const int* src = (const int*)d_in[4];
  const int* dst = (const int*)d_in[5];
  float* out = (float*)d_out;

  // Workspace layout (16-int aligned chunks)
  unsigned short* hwb = (unsigned short*)d_ws;       // NN*MF bf16 (6.4 MB)
  int* histT = (int*)(hwb + (size_t)NN * MF);        // NBK*64
  int* bucketStart = histT + NBK * 64;               // NBK (+pad)
  int* bucketCnt = bucketStart + ((NBK + 15) & ~15);
  int* offs = bucketCnt + ((NBK + 15) & ~15);        // NN
  int* ends = offs + ((NN + 15) & ~15);              // NN
  int* eidx = ends + ((NN + 15) & ~15);              // EIDX_CAP
  int* eidx2 = eidx + ((EIDX_CAP + 15) & ~15);       // EIDX_CAP
  const size_t need =
      ((size_t)NN * MF / 2 + NBK * 64 + 2 * ((NBK + 15) & ~15) +
       2 * ((NN + 15) & ~15) + 2 * ((EIDX_CAP + 15) & ~15)) * 4;
  if (ws_size < need) return;

  gemm_hist<<<GB + HB, 256, 0, stream>>>(h, W, norm, dst, hwb, histT);
  scatter_scan<<<HB, 1024, 0, stream>>>(src, dst, histT, eidx, bucketStart, bucketCnt);
  csr_sort<<<NBK, 256, 0, stream>>>(bucketStart, bucketCnt, eidx, eidx2, offs, ends);
  gather_finalize<<<(NN + 3) / 4, 256, 0, stream>>>(offs, ends, eidx2, hwb, norm, bias, out);
}

// Round 7
// 172.483 us; speedup vs baseline: 2.8802x; 1.0304x over previous
//
#include <hip/hip_runtime.h>

#define NN 50000
#define NE 800000
#define KF 256
#define MF 64

#define NBK 782    // node buckets of 64: ceil(50000/64)
#define HB 49      // hist/scatter blocks
#define EPB 16384  // edges per hist/scatter block (49*16384 >= 800000)
#define GB 782     // gemm blocks (ceil(50000/64))
#define EIDX_CAP (NE + 16 * NBK)  // padded bucket regions

typedef __attribute__((ext_vector_type(8))) short short8;
typedef __attribute__((ext_vector_type(4))) float f32x4;

static __device__ __forceinline__ unsigned short f2bf(float x) {
  unsigned int u = __float_as_uint(x);
  u += 0x7FFF + ((u >> 16) & 1);  // round-nearest-even
  return (unsigned short)(u >> 16);
}
static __device__ __forceinline__ float bf2f(unsigned short u) {
  return __uint_as_float(((unsigned int)u) << 16);
}

// ------- Prepack W (fp32 [k][n]) into B-fragment-ordered bf16 table --------
// Entry f = (k0i*4 + nt)*64 + lane holds B[k=k0i*32+quad*8+j][n=nt*16+m],
// j=0..7, m=lane&15, quad=lane>>4. GEMM's B-load = contiguous 1 KB/wave,
// table is 32 KB -> L1-resident per CU.
__global__ __launch_bounds__(256) void prepack_w(
    const float* __restrict__ W, unsigned short* __restrict__ wtab) {
  const int f = blockIdx.x * 256 + threadIdx.x;  // 0..2047
  const int m = f & 15;
  const int quad = (f >> 4) & 3;
  const int nt = (f >> 6) & 3;
  const int k0i = f >> 8;
  const int n = nt * 16 + m;
  const int kb = k0i * 32 + quad * 8;
  short8 p;
#pragma unroll
  for (int j = 0; j < 8; ++j) p[j] = (short)f2bf(W[(kb + j) * MF + n]);
  *(short8*)(wtab + (size_t)f * 8) = p;
}

// ------- Fused: LDS-free MFMA GEMM (blocks 0..781) + histogram (782..830) --
// gemm: hwb[i][j] = bf16((h@W)[i][j] * norm[i]). A-fragments loaded directly
// from global as 2x float4 per k-step (each h byte read once), B-fragments
// from L1-resident wtab. No __shared__, no barrier in the gemm branch.
__global__ __launch_bounds__(256, 4) void gemm_hist(
    const float* __restrict__ h, const unsigned short* __restrict__ wtab,
    const float* __restrict__ norm, const int* __restrict__ dst,
    unsigned short* __restrict__ hwb, int* __restrict__ histT) {
  __shared__ int hh[NBK];  // hist branch only (3.1 KB)
  const int t = threadIdx.x;

  if (blockIdx.x >= GB) {  // ---- histogram branch ----
    const int hb = blockIdx.x - GB;
    for (int i = t; i < NBK; i += 256) hh[i] = 0;
    __syncthreads();
    const int base = hb * EPB;
#pragma unroll
    for (int i = 0; i < EPB / 256; ++i) {
      const int e = base + i * 256 + t;
      if (e < NE) atomicAdd(&hh[dst[e] >> 6], 1);
    }
    __syncthreads();
    for (int i = t; i < NBK; i += 256) histT[i * 64 + hb] = hh[i];
    return;
  }

  // ---- GEMM branch ----
  const int lane = t & 63;
  const int wv = t >> 6;       // 0..3
  const int m = lane & 15;
  const int quad = lane >> 4;  // 0..3
  const int row0 = blockIdx.x * 64;
  const int arow = row0 + wv * 16 + m;
  const int rowc = (arow < NN) ? arow : (NN - 1);  // clamp; store is guarded
  const float* ap = h + (size_t)rowc * KF + quad * 8;
  const short8* wp = (const short8*)wtab;

  f32x4 acc[4];
#pragma unroll
  for (int i = 0; i < 4; ++i) acc[i] = (f32x4){0.f, 0.f, 0.f, 0.f};

#pragma unroll 2
  for (int k0i = 0; k0i < 8; ++k0i) {
    const float4 a0 = *(const float4*)(ap + k0i * 32);
    const float4 a1 = *(const float4*)(ap + k0i * 32 + 4);
    short8 af;
    af[0] = (short)f2bf(a0.x); af[1] = (short)f2bf(a0.y);
    af[2] = (short)f2bf(a0.z); af[3] = (short)f2bf(a0.w);
    af[4] = (short)f2bf(a1.x); af[5] = (short)f2bf(a1.y);
    af[6] = (short)f2bf(a1.z); af[7] = (short)f2bf(a1.w);
    const short8* wk = wp + k0i * 4 * 64 + lane;
#pragma unroll
    for (int nt = 0; nt < 4; ++nt) {
      const short8 bf = wk[nt * 64];  // 1 KB contiguous per wave, L1 hit
      acc[nt] = __builtin_amdgcn_mfma_f32_16x16x32_bf16(af, bf, acc[nt], 0, 0, 0);
    }
  }

  // Epilogue: D row = quad*4 + r, col = nt*16 + m
  const int gm0 = row0 + wv * 16 + quad * 4;
  float nrm[4];
#pragma unroll
  for (int r = 0; r < 4; ++r) nrm[r] = (gm0 + r < NN) ? norm[gm0 + r] : 0.f;
#pragma unroll
  for (int nt = 0; nt < 4; ++nt) {
#pragma unroll
    for (int r = 0; r < 4; ++r) {
      const int gm = gm0 + r;
      if (gm < NN) hwb[(size_t)gm * MF + nt * 16 + m] = f2bf(acc[nt][r] * nrm[r]);
    }
  }
}

// ------- Scatter with integrated scan: every block recomputes bucket bases -
__global__ __launch_bounds__(1024) void scatter_scan(
    const int* __restrict__ src, const int* __restrict__ dst,
    const int* __restrict__ histT, int* __restrict__ eidx,
    int* __restrict__ bucketStart, int* __restrict__ bucketCnt) {
  __shared__ int s[1024];
  __shared__ int cur[NBK];
  const int t = threadIdx.x;
  int tot = 0, mine = 0;
  if (t < NBK) {
    const int* hp = histT + t * 64;  // contiguous per thread
#pragma unroll
    for (int b = 0; b < HB; ++b) {
      const int v = hp[b];
      if (b < (int)blockIdx.x) mine += v;
      tot += v;
    }
  }
  const int pad = (tot + 15) & ~15;  // 64 B-align bucket regions
  s[t] = (t < NBK) ? pad : 0;
  __syncthreads();
  for (int off = 1; off < 1024; off <<= 1) {
    const int a = (t >= off) ? s[t - off] : 0;
    __syncthreads();
    s[t] += a;
    __syncthreads();
  }
  if (t < NBK) {
    const int start = s[t] - pad;  // exclusive prefix
    cur[t] = start + mine;
    if (blockIdx.x == 0) {
      bucketStart[t] = start;
      bucketCnt[t] = tot;
    }
  }
  __syncthreads();
  const int base = blockIdx.x * EPB;
#pragma unroll
  for (int i = 0; i < EPB / 1024; ++i) {
    const int e = base + i * 1024 + t;
    if (e < NE) {
      const int d = dst[e];
      const int pos = atomicAdd(&cur[d >> 6], 1);
      eidx[pos] = (src[e] << 6) | (d & 63);  // src<65536 -> fits
    }
  }
}

// ------- Per-bucket counting sort -> exact per-node CSR --------------------
__global__ __launch_bounds__(256) void csr_sort(
    const int* __restrict__ bucketStart, const int* __restrict__ bucketCnt,
    const int* __restrict__ eidx, int* __restrict__ eidx2,
    int* __restrict__ offs, int* __restrict__ ends) {
  __shared__ int hcnt[64];
  __shared__ int cur[64];
  const int t = threadIdx.x;
  const int g = blockIdx.x;
  const int beg = __builtin_amdgcn_readfirstlane(bucketStart[g]);
  const int cnt = __builtin_amdgcn_readfirstlane(bucketCnt[g]);
  if (t < 64) hcnt[t] = 0;
  __syncthreads();
  for (int i = t; i < cnt; i += 256) atomicAdd(&hcnt[eidx[beg + i] & 63], 1);
  __syncthreads();
  if (t < 64) {  // wave 0: 64-lane exclusive scan
    const int v = hcnt[t];
    int incl = v;
#pragma unroll
    for (int off = 1; off < 64; off <<= 1) {
      const int u = __shfl_up(incl, off, 64);
      if (t >= off) incl += u;
    }
    const int excl = incl - v;
    cur[t] = excl;
    const int vtx = g * 64 + t;
    if (vtx < NN) {
      offs[vtx] = beg + excl;
      ends[vtx] = beg + excl + v;
    }
  }
  __syncthreads();
  for (int i = t; i < cnt; i += 256) {
    const int val = eidx[beg + i];
    const int p = atomicAdd(&cur[val & 63], 1);
    eidx2[beg + p] = val >> 6;  // src node id
  }
}

// ------- CSR gather (bf16 rows) + fused epilogue ---------------------------
__global__ __launch_bounds__(256) void gather_finalize(
    const int* __restrict__ offs, const int* __restrict__ ends,
    const int* __restrict__ eidx2, const unsigned short* __restrict__ hwb,
    const float* __restrict__ norm, const float* __restrict__ bias,
    float* __restrict__ out) {
  const int t = threadIdx.x;
  const int lane = t & 63;
  const int v = blockIdx.x * 4 + (t >> 6);
  if (v >= NN) return;
  const int beg = __builtin_amdgcn_readfirstlane(offs[v]);
  const int end = __builtin_amdgcn_readfirstlane(ends[v]);
  float acc = 0.f;
  int i = beg;
  for (; i + 8 <= end; i += 8) {  // 8 row-loads in flight
    const int s0 = eidx2[i], s1 = eidx2[i + 1], s2 = eidx2[i + 2], s3 = eidx2[i + 3];
    const int s4 = eidx2[i + 4], s5 = eidx2[i + 5], s6 = eidx2[i + 6], s7 = eidx2[i + 7];
    const unsigned short x0 = hwb[(size_t)s0 * MF + lane];
    const unsigned short x1 = hwb[(size_t)s1 * MF + lane];
    const unsigned short x2 = hwb[(size_t)s2 * MF + lane];
    const unsigned short x3 = hwb[(size_t)s3 * MF + lane];
    const unsigned short x4 = hwb[(size_t)s4 * MF + lane];
    const unsigned short x5 = hwb[(size_t)s5 * MF + lane];
    const unsigned short x6 = hwb[(size_t)s6 * MF + lane];
    const unsigned short x7 = hwb[(size_t)s7 * MF + lane];
    acc += bf2f(x0); acc += bf2f(x1); acc += bf2f(x2); acc += bf2f(x3);
    acc += bf2f(x4); acc += bf2f(x5); acc += bf2f(x6); acc += bf2f(x7);
  }
  for (; i + 2 <= end; i += 2) {
    const int s0 = eidx2[i], s1 = eidx2[i + 1];
    const unsigned short x0 = hwb[(size_t)s0 * MF + lane];
    const unsigned short x1 = hwb[(size_t)s1 * MF + lane];
    acc += bf2f(x0); acc += bf2f(x1);
  }
  if (i < end) acc += bf2f(hwb[(size_t)eidx2[i] * MF + lane]);
  const float o = acc * norm[v] + bias[lane];
  out[(size_t)v * MF + lane] = fmaxf(o, 0.f);
}

extern "C" void kernel_launch(void* const* d_in, const int* in_sizes, int n_in,
                              void* d_out, int out_size, void* d_ws, size_t ws_size,
                              hipStream_t stream) {
  const float* h = (const float*)d_in[0];
  const float* norm = (const float*)d_in[1];
  const float* W = (const float*)d_in[2];
  const float* bias = (const float*)d_in[3];
  const int* src = (const int*)d_in[4];
  const int* dst = (const int*)d_in[5];
  float* out = (float*)d_out;

  // Workspace layout (16-int aligned chunks)
  unsigned short* hwb = (unsigned short*)d_ws;       // NN*MF bf16 (6.4 MB)
  unsigned short* wtab = hwb + (size_t)NN * MF;      // 16384 bf16 (32 KB)
  int* histT = (int*)(wtab + 16384);                 // NBK*64
  int* bucketStart = histT + NBK * 64;               // NBK (+pad)
  int* bucketCnt = bucketStart + ((NBK + 15) & ~15);
  int* offs = bucketCnt + ((NBK + 15) & ~15);        // NN
  int* ends = offs + ((NN + 15) & ~15);              // NN
  int* eidx = ends + ((NN + 15) & ~15);              // EIDX_CAP
  int* eidx2 = eidx + ((EIDX_CAP + 15) & ~15);       // EIDX_CAP
  const size_t need =
      ((size_t)NN * MF / 2 + 8192 + NBK * 64 + 2 * ((NBK + 15) & ~15) +
       2 * ((NN + 15) & ~15) + 2 * ((EIDX_CAP + 15) & ~15)) * 4;
  if (ws_size < need) return;

  prepack_w<<<8, 256, 0, stream>>>(W, wtab);
  gemm_hist<<<GB + HB, 256, 0, stream>>>(h, wtab, norm, dst, hwb, histT);
  scatter_scan<<<HB, 1024, 0, stream>>>(src, dst, histT, eidx, bucketStart, bucketCnt);
  csr_sort<<<NBK, 256, 0, stream>>>(bucketStart, bucketCnt, eidx, eidx2, offs, ends);
  gather_finalize<<<(NN + 3) / 4, 256, 0, stream>>>(offs, ends, eidx2, hwb, norm, bias, out);
}